// Round 2
// baseline (1433.540 us; speedup 1.0000x reference)
//
#include <hip/hip_runtime.h>

#define Bc 4
#define Tc 1024
#define Dc 1024
#define Hc 16
#define DHc 64
#define Lc 2047

// ---------------------------------------------------------------------------
// Generic fp32 tiled GEMM: C[m,n] = sum_k A[m*lda+k] * Bw[k*ldb+n] (+bias)
// 64x64 tile, BK=16, 256 threads, 4x4 per thread. Optional second output
// (same product, different bias). Batch via blockIdx.z with (b,h) offsets.
// Requires: N % 64 == 0, K % 16 == 0. M arbitrary (guarded).
// ---------------------------------------------------------------------------
__global__ __launch_bounds__(256) void gemm_kernel(
    const float* __restrict__ A, const float* __restrict__ Bw,
    const float* __restrict__ bias1, const float* __restrict__ bias2,
    float* __restrict__ C1, float* __restrict__ C2,
    int M, int N, int K, int lda, int ldb, int ldc,
    long long offA_b, long long offA_h, long long offB_b, long long offB_h,
    long long offC_b, long long offC_h, int Hdiv)
{
    const int z = blockIdx.z;
    const int zb = z / Hdiv, zh = z - zb * Hdiv;
    A  += (size_t)zb * offA_b + (size_t)zh * offA_h;
    Bw += (size_t)zb * offB_b + (size_t)zh * offB_h;
    C1 += (size_t)zb * offC_b + (size_t)zh * offC_h;
    float* C2l = C2 ? C2 + (size_t)zb * offC_b + (size_t)zh * offC_h : nullptr;

    const int m0 = blockIdx.y << 6, n0 = blockIdx.x << 6;
    const int tx = threadIdx.x, ty = threadIdx.y;
    const int tid = ty * 16 + tx;

    __shared__ float AsT[16][64];   // [k][m] transposed for conflict-free b128 reads
    __shared__ float Bs[16][64];    // [k][n]

    float acc[4][4] = {};

    const int arow = tid >> 2, ac4 = (tid & 3) << 2;   // A tile: 64 rows x 16 k
    const int brow = tid >> 4, bc4 = (tid & 15) << 2;  // B tile: 16 k x 64 n

    for (int k0 = 0; k0 < K; k0 += 16) {
        float4 av = make_float4(0.f, 0.f, 0.f, 0.f);
        if (m0 + arow < M)
            av = *(const float4*)(A + (size_t)(m0 + arow) * lda + k0 + ac4);
        AsT[ac4 + 0][arow] = av.x;
        AsT[ac4 + 1][arow] = av.y;
        AsT[ac4 + 2][arow] = av.z;
        AsT[ac4 + 3][arow] = av.w;
        float4 bv = *(const float4*)(Bw + (size_t)(k0 + brow) * ldb + n0 + bc4);
        *(float4*)&Bs[brow][bc4] = bv;
        __syncthreads();
        #pragma unroll
        for (int kk = 0; kk < 16; ++kk) {
            const float4 a4 = *(const float4*)&AsT[kk][ty << 2];
            const float4 b4 = *(const float4*)&Bs[kk][tx << 2];
            const float aa[4] = {a4.x, a4.y, a4.z, a4.w};
            const float bb[4] = {b4.x, b4.y, b4.z, b4.w};
            #pragma unroll
            for (int i = 0; i < 4; ++i)
                #pragma unroll
                for (int j = 0; j < 4; ++j)
                    acc[i][j] += aa[i] * bb[j];
        }
        __syncthreads();
    }

    float b1[4] = {0.f, 0.f, 0.f, 0.f};
    float b2[4] = {0.f, 0.f, 0.f, 0.f};
    if (bias1) {
        #pragma unroll
        for (int j = 0; j < 4; ++j) b1[j] = bias1[n0 + (tx << 2) + j];
    }
    if (bias2) {
        #pragma unroll
        for (int j = 0; j < 4; ++j) b2[j] = bias2[n0 + (tx << 2) + j];
    }

    #pragma unroll
    for (int i = 0; i < 4; ++i) {
        const int row = m0 + (ty << 2) + i;
        if (row < M) {
            float4 o;
            o.x = acc[i][0] + b1[0];
            o.y = acc[i][1] + b1[1];
            o.z = acc[i][2] + b1[2];
            o.w = acc[i][3] + b1[3];
            *(float4*)(C1 + (size_t)row * ldc + n0 + (tx << 2)) = o;
            if (C2l) {
                float4 o2;
                o2.x = acc[i][0] + b2[0];
                o2.y = acc[i][1] + b2[1];
                o2.z = acc[i][2] + b2[2];
                o2.w = acc[i][3] + b2[3];
                *(float4*)(C2l + (size_t)row * ldc + n0 + (tx << 2)) = o2;
            }
        }
    }
}

// ---------------------------------------------------------------------------
// Fused relative-attention scores:
//   att[b,h,t,s] = (Qu[t]·K[s] + Qv[t]·E[1023 - t + s]) / 8 + mask[b,s]*(-1e7)
// 64x64 (t,s) tile per block, 256 threads, 4x4 per thread. E comes from a
// 127-row band: local band index j = 63 - t_loc + s_loc in [0,126], and the
// global row r = (960 - t0 + s0) + j is always within [0, 2046].
// ---------------------------------------------------------------------------
__global__ __launch_bounds__(256) void scores_kernel(
    const float* __restrict__ Qu, const float* __restrict__ Qv,
    const float* __restrict__ Kx, const float* __restrict__ E,
    const int* __restrict__ mask, float* __restrict__ att)
{
    const int bh = blockIdx.z, b = bh >> 4, h = bh & 15;
    const int t0 = blockIdx.y << 6, s0 = blockIdx.x << 6;
    const int tx = threadIdx.x, ty = threadIdx.y;
    const int tid = ty * 16 + tx;

    __shared__ float QusT[16][64];   // [k][t]
    __shared__ float QvsT[16][64];   // [k][t]
    __shared__ float KsT[16][64];    // [k][s]
    __shared__ float EsT[16][128];   // [k][band j], rows 0..126 used

    const float* Qub = Qu + ((size_t)(b * Tc + t0)) * Dc + h * DHc;
    const float* Qvb = Qv + ((size_t)(b * Tc + t0)) * Dc + h * DHc;
    const float* Kb  = Kx + ((size_t)(b * Tc + s0)) * Dc + h * DHc;
    const int r0 = 960 - t0 + s0;                      // band start, always >= 0
    const float* Ebnd = E + (size_t)r0 * Dc + h * DHc;

    float accK[4][4] = {};
    float accE[4][4] = {};

    const int qrow = tid >> 2, qc4 = (tid & 3) << 2;   // 64 rows x 16 k
    const int erow = tid >> 1, ec8 = (tid & 1) << 3;   // 128 rows x 16 k (127 valid)
    const int ebase = 60 + ((tx - ty) << 2);           // in [0,120], multiple of 4

    for (int k0 = 0; k0 < DHc; k0 += 16) {
        {
            float4 a  = *(const float4*)(Qub + (size_t)qrow * Dc + k0 + qc4);
            float4 bq = *(const float4*)(Qvb + (size_t)qrow * Dc + k0 + qc4);
            float4 kv = *(const float4*)(Kb  + (size_t)qrow * Dc + k0 + qc4);
            QusT[qc4 + 0][qrow] = a.x;  QusT[qc4 + 1][qrow] = a.y;
            QusT[qc4 + 2][qrow] = a.z;  QusT[qc4 + 3][qrow] = a.w;
            QvsT[qc4 + 0][qrow] = bq.x; QvsT[qc4 + 1][qrow] = bq.y;
            QvsT[qc4 + 2][qrow] = bq.z; QvsT[qc4 + 3][qrow] = bq.w;
            KsT[qc4 + 0][qrow] = kv.x;  KsT[qc4 + 1][qrow] = kv.y;
            KsT[qc4 + 2][qrow] = kv.z;  KsT[qc4 + 3][qrow] = kv.w;
        }
        if (erow < 127) {
            float4 e0 = *(const float4*)(Ebnd + (size_t)erow * Dc + k0 + ec8);
            float4 e1 = *(const float4*)(Ebnd + (size_t)erow * Dc + k0 + ec8 + 4);
            EsT[ec8 + 0][erow] = e0.x; EsT[ec8 + 1][erow] = e0.y;
            EsT[ec8 + 2][erow] = e0.z; EsT[ec8 + 3][erow] = e0.w;
            EsT[ec8 + 4][erow] = e1.x; EsT[ec8 + 5][erow] = e1.y;
            EsT[ec8 + 6][erow] = e1.z; EsT[ec8 + 7][erow] = e1.w;
        }
        __syncthreads();
        #pragma unroll
        for (int kk = 0; kk < 16; ++kk) {
            const float4 qu4 = *(const float4*)&QusT[kk][ty << 2];
            const float4 qv4 = *(const float4*)&QvsT[kk][ty << 2];
            const float4 kf4 = *(const float4*)&KsT[kk][tx << 2];
            const float4 e0  = *(const float4*)&EsT[kk][ebase];
            const float4 e1  = *(const float4*)&EsT[kk][ebase + 4];
            const float qua[4] = {qu4.x, qu4.y, qu4.z, qu4.w};
            const float qva[4] = {qv4.x, qv4.y, qv4.z, qv4.w};
            const float kfa[4] = {kf4.x, kf4.y, kf4.z, kf4.w};
            const float ef[8]  = {e0.x, e0.y, e0.z, e0.w, e1.x, e1.y, e1.z, e1.w};
            #pragma unroll
            for (int i = 0; i < 4; ++i) {
                #pragma unroll
                for (int j = 0; j < 4; ++j) {
                    accK[i][j] += qua[i] * kfa[j];
                    accE[i][j] += qva[i] * ef[j - i + 3];   // band offset j-i+3 in [0,6]
                }
            }
        }
        __syncthreads();
    }

    const int* mb = mask + b * Tc + s0;
    float mk[4];
    #pragma unroll
    for (int j = 0; j < 4; ++j) mk[j] = (float)mb[(tx << 2) + j] * (-1e7f);

    float* out = att + (((size_t)bh * Tc + t0 + (ty << 2)) * Tc) + s0 + (tx << 2);
    #pragma unroll
    for (int i = 0; i < 4; ++i) {
        float4 o;
        o.x = (accK[i][0] + accE[i][0]) * 0.125f + mk[0];
        o.y = (accK[i][1] + accE[i][1]) * 0.125f + mk[1];
        o.z = (accK[i][2] + accE[i][2]) * 0.125f + mk[2];
        o.w = (accK[i][3] + accE[i][3]) * 0.125f + mk[3];
        *(float4*)(out + (size_t)i * Tc) = o;
    }
}

// ---------------------------------------------------------------------------
// Row softmax over the last dim (1024), in place. One block (256 thr) per row.
// ---------------------------------------------------------------------------
__global__ __launch_bounds__(256) void softmax_kernel(float* __restrict__ att)
{
    const size_t row = blockIdx.x;
    float* p = att + row * Tc;
    const int tid = threadIdx.x;
    const int wave = tid >> 6, lane = tid & 63;

    float4 v = *(float4*)(p + (tid << 2));
    float m = fmaxf(fmaxf(v.x, v.y), fmaxf(v.z, v.w));
    #pragma unroll
    for (int off = 32; off >= 1; off >>= 1)
        m = fmaxf(m, __shfl_xor(m, off, 64));

    __shared__ float redm[4];
    if (lane == 0) redm[wave] = m;
    __syncthreads();
    m = fmaxf(fmaxf(redm[0], redm[1]), fmaxf(redm[2], redm[3]));

    float4 e;
    e.x = expf(v.x - m);
    e.y = expf(v.y - m);
    e.z = expf(v.z - m);
    e.w = expf(v.w - m);
    float s = e.x + e.y + e.z + e.w;
    #pragma unroll
    for (int off = 32; off >= 1; off >>= 1)
        s += __shfl_xor(s, off, 64);

    __shared__ float reds[4];
    if (lane == 0) reds[wave] = s;
    __syncthreads();
    s = reds[0] + reds[1] + reds[2] + reds[3];

    const float inv = 1.0f / s;
    e.x *= inv; e.y *= inv; e.z *= inv; e.w *= inv;
    *(float4*)(p + (tid << 2)) = e;
}

// ---------------------------------------------------------------------------
extern "C" void kernel_launch(void* const* d_in, const int* in_sizes, int n_in,
                              void* d_out, int out_size, void* d_ws, size_t ws_size,
                              hipStream_t stream)
{
    const float* qkv   = (const float*)d_in[0];
    const int*   amask = (const int*)d_in[1];
    const float* pose  = (const float*)d_in[2];
    const float* Wq    = (const float*)d_in[3];
    const float* Wk    = (const float*)d_in[4];
    const float* Wv    = (const float*)d_in[5];
    const float* Wpos  = (const float*)d_in[6];
    const float* bpos  = (const float*)d_in[7];
    const float* Wo    = (const float*)d_in[8];
    const float* u     = (const float*)d_in[9];
    const float* vvec  = (const float*)d_in[10];

    float* out_O   = (float*)d_out;                          // (B,T,D)
    float* out_att = (float*)d_out + (size_t)Bc * Tc * Dc;   // (B,H,T,T)

    float* ws = (float*)d_ws;
    const size_t SZ_BTD = (size_t)Bc * Tc * Dc;   // 4M floats
    float* Qu = ws;
    float* Qv = Qu + SZ_BTD;
    float* Kb = Qv + SZ_BTD;
    float* Vb = Kb + SZ_BTD;
    float* Eb = Vb + SZ_BTD;                       // L*D floats
    float* Op = Eb + (size_t)Lc * Dc;              // (B,T,D) pre-Wo

    dim3 blk(16, 16);

    // Projections: Qu/Qv (fused, two biases), K, V, E(+bpos)
    gemm_kernel<<<dim3(16, 64, 1), blk, 0, stream>>>(
        qkv, Wq, u, vvec, Qu, Qv,
        Bc * Tc, Dc, Dc, Dc, Dc, Dc, 0, 0, 0, 0, 0, 0, 1);
    gemm_kernel<<<dim3(16, 64, 1), blk, 0, stream>>>(
        qkv, Wk, nullptr, nullptr, Kb, nullptr,
        Bc * Tc, Dc, Dc, Dc, Dc, Dc, 0, 0, 0, 0, 0, 0, 1);
    gemm_kernel<<<dim3(16, 64, 1), blk, 0, stream>>>(
        qkv, Wv, nullptr, nullptr, Vb, nullptr,
        Bc * Tc, Dc, Dc, Dc, Dc, Dc, 0, 0, 0, 0, 0, 0, 1);
    gemm_kernel<<<dim3(16, 32, 1), blk, 0, stream>>>(
        pose, Wpos, bpos, nullptr, Eb, nullptr,
        Lc, Dc, Dc, Dc, Dc, Dc, 0, 0, 0, 0, 0, 0, 1);

    // Fused scores (K-term + relative E-term + mask), pre-softmax
    scores_kernel<<<dim3(16, 16, Bc * Hc), blk, 0, stream>>>(
        Qu, Qv, Kb, Eb, amask, out_att);

    // Softmax in place -> att_w output
    softmax_kernel<<<dim3(Bc * Hc * Tc), dim3(256), 0, stream>>>(out_att);

    // O_pre[b,t,h*64+d] = sum_s att[b,h,t,s] * V[b,s,h*64+d]
    gemm_kernel<<<dim3(1, 16, Bc * Hc), blk, 0, stream>>>(
        out_att, Vb, nullptr, nullptr, Op, nullptr,
        Tc, DHc, Tc, Tc, Dc, Dc,
        (long long)Hc * Tc * Tc, (long long)Tc * Tc,
        (long long)Tc * Dc, (long long)DHc,
        (long long)Tc * Dc, (long long)DHc, Hc);

    // Output projection
    gemm_kernel<<<dim3(16, 64, 1), blk, 0, stream>>>(
        Op, Wo, nullptr, nullptr, out_O, nullptr,
        Bc * Tc, Dc, Dc, Dc, Dc, Dc, 0, 0, 0, 0, 0, 0, 1);
}